// Round 22
// baseline (617.975 us; speedup 1.0000x reference)
//
#include <hip/hip_runtime.h>

typedef __attribute__((ext_vector_type(8))) __bf16 bf16x8;
typedef __attribute__((ext_vector_type(4))) __bf16 bf16x4;
typedef __attribute__((ext_vector_type(4))) float f32x4;
typedef __attribute__((ext_vector_type(16))) float f32x16;

#define LL 2048
#define DD 2048
#define HH 16
#define HDIM 128

// ---------------- merged setup: conversions + builders + counter zeroing -------
__global__ __launch_bounds__(256)
void setup_all(const float* __restrict__ x, const float* __restrict__ Wq,
               const float* __restrict__ Wk, const float* __restrict__ Wqc,
               const float* __restrict__ Wkc,
               const float* __restrict__ Wv, const float* __restrict__ Wvc,
               const float* __restrict__ bv, const float* __restrict__ bvc,
               const float* __restrict__ Wo, const float* __restrict__ Wd,
               const float* __restrict__ bd, const float* __restrict__ bo,
               __bf16* __restrict__ xb, __bf16* __restrict__ Wqb, __bf16* __restrict__ Wkb,
               __bf16* __restrict__ Wqcb, __bf16* __restrict__ Wkcb,
               __bf16* __restrict__ Wveff, float* __restrict__ bveff,
               __bf16* __restrict__ Woeff, float* __restrict__ boeff,
               int* __restrict__ cnt)
{
    __shared__ float sm[128 * 32];
    const int tid = threadIdx.x;
    const int bid = blockIdx.x;

    if (bid < 16392) {                                    // fp32 -> bf16 conversions
        size_t i = (size_t)bid * 256 + tid;
        const float* s; __bf16* d; size_t off;
        if (i < 2097152)      { s = x;   d = xb;   off = i; }
        else if (i < 3145728) { s = Wq;  d = Wqb;  off = i - 2097152; }
        else if (i < 4194304) { s = Wk;  d = Wkb;  off = i - 3145728; }
        else if (i < 4195328) { s = Wqc; d = Wqcb; off = i - 4194304; }
        else                  { s = Wkc; d = Wkcb; off = i - 4195328; }
        float4 v = *(const float4*)(s + off * 4);
        bf16x4 o = { (__bf16)v.x, (__bf16)v.y, (__bf16)v.z, (__bf16)v.w };
        *(bf16x4*)(d + off * 4) = o;
        return;
    }
    int idx = bid - 16392;
    if (idx < 512) {                                      // Wv_eff
        float (*WvcT)[32] = (float(*)[32])sm;             // [j][o]
        const int h = idx >> 5, dc = idx & 31;
        for (int i = tid; i < 4096; i += 256) WvcT[i & 127][i >> 7] = Wvc[i];
        __syncthreads();
        const int d  = dc * 64 + (tid & 63);
        const int o0 = (tid >> 6) * 8;
        float acc[8] = {};
        for (int jj = 0; jj < 128; ++jj) {
            const float w = Wv[(size_t)(h * 128 + jj) * 2048 + d];
            #pragma unroll
            for (int o = 0; o < 8; ++o) acc[o] += WvcT[jj][o0 + o] * w;
        }
        #pragma unroll
        for (int o = 0; o < 8; ++o)
            Wveff[(size_t)(h * 32 + o0 + o) * 2048 + d] = (__bf16)acc[o];
        if (dc == 0 && tid < 32) {
            float s = bvc[tid];
            for (int jj = 0; jj < 128; ++jj) s += WvcT[jj][tid] * bv[h * 128 + jj];
            bveff[h * 32 + tid] = s;
        }
        return;
    }
    idx -= 512;
    if (idx < 512) {                                      // Wo_eff
        float (*WdL)[32] = (float(*)[32])sm;              // [u][o]
        const int dc = idx & 31, h = idx >> 5;
        for (int i = tid; i < 4096; i += 256) WdL[i >> 5][i & 31] = Wd[i];
        __syncthreads();
        const int dout = dc * 64 + (tid & 63);
        const int o0   = (tid >> 6) * 8;
        float acc[8] = {};
        const float* wrow = Wo + (size_t)dout * 2048 + h * 128;
        for (int u = 0; u < 128; ++u) {
            const float w = wrow[u];
            #pragma unroll
            for (int o = 0; o < 8; ++o) acc[o] += WdL[u][o0 + o] * w;
        }
        #pragma unroll
        for (int o = 0; o < 8; ++o)
            Woeff[(size_t)dout * 512 + h * 32 + o0 + o] = (__bf16)acc[o];
        return;
    }
    idx -= 512;
    if (idx < 64) {                                       // bo_eff
        float* bdL = sm;
        if (tid < 128) bdL[tid] = bd[tid];
        __syncthreads();
        const int d  = idx * 32 + (tid >> 3);
        const int s0 = (tid & 7) * 64;
        float s = 0.f;
        const float* wrow = Wo + (size_t)d * 2048 + s0 * 4;
        for (int c4 = 0; c4 < 64; ++c4) {
            float4 wv = *(const float4*)(wrow + c4 * 4);
            const int cb = ((s0 + c4) * 4) & 127;
            s += wv.x * bdL[cb] + wv.y * bdL[cb + 1] + wv.z * bdL[cb + 2] + wv.w * bdL[cb + 3];
        }
        #pragma unroll
        for (int off = 4; off; off >>= 1) s += __shfl_down(s, off, 8);
        if ((tid & 7) == 0) boeff[d] = bo[d] + s;
        return;
    }
    // counter zeroing (2048 ints) — ws is NOT re-poisoned between replays
    for (int i = tid; i < 2048; i += 256) cnt[i] = 0;
}

// ---------------- global -> LDS async 16B ----------------
typedef unsigned int u32;
typedef const __attribute__((address_space(1))) u32* gp_t;
typedef __attribute__((address_space(3))) u32* lp_t;
__device__ __forceinline__ void gload16(const __bf16* g, __bf16* l)
{
    __builtin_amdgcn_global_load_lds((gp_t)(const void*)g, (lp_t)(void*)l, 16, 0, 0);
}

#define MF16(a, b, c) __builtin_amdgcn_mfma_f32_16x16x32_bf16(a, b, c, 0, 0, 0)

// ====== 128x256-tile fused QKV GEMM + in-epilogue RoPE+latproj (q,k) ============
__global__ __launch_bounds__(256, 2)
void gemm_qkv(const __bf16* __restrict__ A,
              const __bf16* __restrict__ Wq, const __bf16* __restrict__ Wk,
              const __bf16* __restrict__ Wveff,
              const float* __restrict__ bq, const float* __restrict__ bk,
              const float* __restrict__ bveff,
              const __bf16* __restrict__ Wqcb, const __bf16* __restrict__ Wkcb,
              const float* __restrict__ bqc, const float* __restrict__ bkc,
              const float* __restrict__ fc,
              __bf16* __restrict__ qc, __bf16* __restrict__ kc, __bf16* __restrict__ vt)
{
    __shared__ __bf16 lds[3][12288];    // per buf: A[128][32] @0, B[256][32] @4096

    const int bid = blockIdx.x;                 // 576
    const int xcd = bid & 7;
    const int j   = bid >> 3;                   // 0..71
    const int bx  = j >> 2;                     // 0..17
    const int byl = j & 3;
    const int by  = xcd * 4 + byl;              // 0..31
    const int m0  = by * 128;
    const int which = (bx >= 16) ? 2 : (bx >> 3);
    const int n0  = (which == 2) ? (bx - 16) * 256 : (bx & 7) * 256;
    const __bf16* W = which == 0 ? Wq : which == 1 ? Wk : Wveff;

    const int tid  = threadIdx.x;
    const int wid  = tid >> 6;
    const int lane = tid & 63;
    const int wr   = wid >> 1;
    const int wc   = wid & 1;
    const int l15  = lane & 15;
    const int l4   = lane >> 4;
    const int swz  = (l4 ^ (l15 & 3) ^ ((l15 >> 2) & 3)) * 8;

    const int srl  = lane >> 2;
    const int scol = ((lane & 3) ^ (srl & 3) ^ ((srl >> 2) & 3)) * 8;
    const __bf16* gA0 = A + (size_t)(m0 + wid * 32 + srl) * 2048 + scol;
    const __bf16* gB0 = W + (size_t)(n0 + wid * 64 + srl) * 2048 + scol;

    #define STAGE(bb, kk)                                                \
    {   __bf16* dA = &lds[bb][wid * 1024];                               \
        __bf16* dB = &lds[bb][4096 + wid * 2048];                        \
        gload16(gA0 + (kk), dA);                                         \
        gload16(gA0 + (size_t)16 * 2048 + (kk), dA + 512);               \
        gload16(gB0 + (kk), dB);                                         \
        gload16(gB0 + (size_t)16 * 2048 + (kk), dB + 512);               \
        gload16(gB0 + (size_t)32 * 2048 + (kk), dB + 1024);              \
        gload16(gB0 + (size_t)48 * 2048 + (kk), dB + 1536);              \
    }
    #define RD_A(bb, mf) (*(const bf16x8*)&lds[bb][(wr * 64 + (mf) * 16 + l15) * 32 + swz])
    #define RD_B(bb, nf) (*(const bf16x8*)&lds[bb][4096 + (wc * 128 + (nf) * 16 + l15) * 32 + swz])

    f32x4 acc[4][8] = {};

    STAGE(0, 0) STAGE(1, 32)
    asm volatile("s_waitcnt vmcnt(6)" ::: "memory");
    __builtin_amdgcn_s_barrier();

    #define TB(RB, SB, VM, DOST, kk)                                          \
    {                                                                         \
        bf16x8 fa[4], fb[8];                                                  \
        fa[0] = RD_A(RB, 0); fa[1] = RD_A(RB, 1);                             \
        fa[2] = RD_A(RB, 2); fa[3] = RD_A(RB, 3);                             \
        fb[0] = RD_B(RB, 0); fb[1] = RD_B(RB, 1);                             \
        fb[2] = RD_B(RB, 2); fb[3] = RD_B(RB, 3);                             \
        fb[4] = RD_B(RB, 4); fb[5] = RD_B(RB, 5);                             \
        fb[6] = RD_B(RB, 6); fb[7] = RD_B(RB, 7);                             \
        if (DOST) STAGE(SB, kk)                                               \
        asm volatile("s_waitcnt lgkmcnt(0)" ::: "memory");                    \
        __builtin_amdgcn_sched_barrier(0);                                    \
        __builtin_amdgcn_s_setprio(1);                                        \
        _Pragma("unroll")                                                     \
        for (int mf = 0; mf < 4; ++mf)                                        \
            _Pragma("unroll")                                                 \
            for (int nf = 0; nf < 8; ++nf)                                    \
                acc[mf][nf] = MF16(fa[mf], fb[nf], acc[mf][nf]);              \
        __builtin_amdgcn_s_setprio(0);                                        \
        asm volatile("s_waitcnt vmcnt(" VM ")" ::: "memory");                 \
        __builtin_amdgcn_s_barrier();                                         \
    }

    for (int tt = 0; tt < 60; tt += 3) {
        const int kk = (tt + 2) * 32;
        TB(0, 2, "6", true, kk)
        TB(1, 0, "6", true, kk + 32)
        TB(2, 1, "6", true, kk + 64)
    }
    TB(0, 2, "6", true, 62 * 32)
    TB(1, 0, "6", true, 63 * 32)
    TB(2, 0, "0", false, 0)
    TB(0, 0, "0", false, 0)
    #undef TB
    #undef STAGE
    #undef RD_A
    #undef RD_B

    if (which < 2) {
        __bf16* qt = &lds[0][0];                // [128][136]
        const float* bb_ = which ? bk : bq;
        const __bf16* Wb = which ? Wkcb : Wqcb;
        const float*  bs = which ? bkc : bqc;
        const int o   = lane & 31;
        const int hi  = lane >> 5;
        const int b   = m0 >> 11;
        const int l0b = m0 & 2047;
        const int lrow = wid * 32 + o;
        const int l    = l0b + lrow;
        const float* fcr = fc + (size_t)l * 128;
        const float QSCALE = 0.17677669529663689f * 1.44269504088896340f;
        __bf16* outp = which ? kc : qc;

        bf16x8 wf[8];
        #pragma unroll
        for (int ks = 0; ks < 8; ++ks)
            wf[ks] = *(const bf16x8*)(Wb + o * 128 + ks * 16 + hi * 8);

        #pragma unroll
        for (int half = 0; half < 2; ++half) {
            if (wc == half) {
                #pragma unroll
                for (int nf = 0; nf < 8; ++nf) {
                    const int col = nf * 16 + l15;
                    const float bv = bb_[n0 + half * 128 + col];
                    #pragma unroll
                    for (int mf = 0; mf < 4; ++mf) {
                        const int row0 = wr * 64 + mf * 16 + l4 * 4;
                        #pragma unroll
                        for (int rr = 0; rr < 4; ++rr)
                            qt[(row0 + rr) * 136 + col] = (__bf16)(acc[mf][nf][rr] + bv);
                    }
                }
            }
            __syncthreads();

            const int h = (n0 >> 7) + half;
            f32x16 C = {};
            #pragma unroll
            for (int ks = 0; ks < 8; ++ks) {
                bf16x8 af = *(const bf16x8*)&qt[lrow * 136 + ks * 16 + hi * 8];
                const float4 cA = *(const float4*)(fcr + (ks * 8 + hi * 4) * 2);
                const float4 cB = *(const float4*)(fcr + (ks * 8 + hi * 4) * 2 + 4);
                float a, b_;
                a = (float)af[0]; b_ = (float)af[1];
                af[0] = (__bf16)(a * cA.x - b_ * cA.y); af[1] = (__bf16)(a * cA.y + b_ * cA.x);
                a = (float)af[2]; b_ = (float)af[3];
                af[2] = (__bf16)(a * cA.z - b_ * cA.w); af[3] = (__bf16)(a * cA.w + b_ * cA.z);
                a = (float)af[4]; b_ = (float)af[5];
                af[4] = (__bf16)(a * cB.x - b_ * cB.y); af[5] = (__bf16)(a * cB.y + b_ * cB.x);
                a = (float)af[6]; b_ = (float)af[7];
                af[6] = (__bf16)(a * cB.z - b_ * cB.w); af[7] = (__bf16)(a * cB.w + b_ * cB.z);
                C = __builtin_amdgcn_mfma_f32_32x32x16_bf16(af, wf[ks], C, 0, 0, 0);
            }

            const float bias = bs[o];
            const size_t g0row = (size_t)(b * 16 + h) * 2048 + l0b + wid * 32;
            #pragma unroll
            for (int r = 0; r < 16; ++r) {
                const int ro = (r & 3) + 8 * (r >> 2) + 4 * hi;
                float v = C[r] + bias;
                if (which == 0) v *= QSCALE;
                outp[(g0row + ro) * 32 + o] = (__bf16)v;
            }
            __syncthreads();
        }
    } else {
        #pragma unroll
        for (int nf = 0; nf < 8; ++nf) {
            const int ncol = n0 + wc * 128 + nf * 16 + l15;
            const float bv = bveff[ncol];
            const int hh = ncol >> 5, oo = ncol & 31;
            #pragma unroll
            for (int mf = 0; mf < 4; ++mf) {
                const int row0 = m0 + wr * 64 + mf * 16 + l4 * 4;
                const int b = row0 >> 11, l0 = row0 & 2047;
                bf16x4 pk = { (__bf16)(acc[mf][nf][0] + bv), (__bf16)(acc[mf][nf][1] + bv),
                              (__bf16)(acc[mf][nf][2] + bv), (__bf16)(acc[mf][nf][3] + bv) };
                *(bf16x4*)(vt + ((size_t)((b * 16 + hh) * 32 + oo)) * 2048 + l0) = pk;
            }
        }
    }
}

// Final GEMM with counted-vmcnt depth-2 pipeline: out = ao@Woeff^T + bo_eff.
__global__ __launch_bounds__(256, 3)
void gemm_ao(const __bf16* __restrict__ ao, const __bf16* __restrict__ Woeff,
             const float* __restrict__ boeff, float* __restrict__ out)
{
    __shared__ __bf16 lds[3][2][4096];          // [buf][A|B][128 rows x 32 cols]
    const int bid = blockIdx.x;                 // 512
    const int xcd = bid & 7;
    const int jj  = bid >> 3;                   // 0..63
    const int by  = xcd * 4 + (jj & 3);         // 0..31
    const int bx  = jj >> 2;                    // 0..15
    const int m0  = by * 128;
    const int n0  = bx * 128;

    const int tid  = threadIdx.x;
    const int wid  = tid >> 6;
    const int lane = tid & 63;
    const int wr   = wid >> 1;
    const int wc   = wid & 1;
    const int l15  = lane & 15;
    const int l4   = lane >> 4;
    const int swz  = (l4 ^ (l15 & 3) ^ ((l15 >> 2) & 3)) * 8;

    const int srl  = lane >> 2;
    const int scol = ((lane & 3) ^ (srl & 3) ^ ((srl >> 2) & 3)) * 8;
    const int r0   = m0 + wid * 32 + srl;
    const int b0   = r0 >> 11, li0 = r0 & 2047;
    const __bf16* gA0 = ao + ((size_t)(b0 << 4) * 2048 + li0) * 32 + scol;
    const __bf16* gA1 = ao + ((size_t)(b0 << 4) * 2048 + li0 + 16) * 32 + scol;
    const __bf16* gB0 = Woeff + (size_t)(n0 + wid * 32 + srl) * 512 + scol;

    #define STAGE(bb, kk)                                                     \
    {   __bf16* dA = &lds[bb][0][wid * 1024];                                 \
        __bf16* dB = &lds[bb][1][wid * 1024];                                 \
        const size_t ka = (size_t)((kk) >> 5) * 65536;                        \
        gload16(gA0 + ka, dA);                                                \
        gload16(gA1 + ka, dA + 512);                                          \
        gload16(gB0 + (kk), dB);                                              \
        gload16(gB0 + (size_t)16 * 512 + (kk), dB + 512);                     \
    }
    #define RD_A(bb, mf) (*(const bf16x8*)&lds[bb][0][(wr * 64 + (mf) * 16 + l15) * 32 + swz])
    #define RD_B(bb, nf) (*(const bf16x8*)&lds[bb][1][(wc * 64 + (nf) * 16 + l15) * 32 + swz])

    f32x4 acc[4][4] = {};

    STAGE(0, 0) STAGE(1, 32)
    asm volatile("s_waitcnt vmcnt(4)" ::: "memory");
    __builtin_amdgcn_s_barrier();

    #define TB(RB, SB, VM, DOST, kk)                                          \
    {                                                                         \
        bf16x8 fa[4], fb[4];                                                  \
        fa[0] = RD_A(RB, 0); fa[1] = RD_A(RB, 1);                             \
        fa[2] = RD_A(RB, 2); fa[3] = RD_A(RB, 3);                             \
        fb[0] = RD_B(RB, 0); fb[1] = RD_B(RB, 1);                             \
        fb[2] = RD_B(RB, 2); fb[3] = RD_B(RB, 3);                             \
        if (DOST) STAGE(SB, kk)                                               \
        asm volatile("s_waitcnt lgkmcnt(0)" ::: "memory");                    \
        __builtin_amdgcn_sched_barrier(0);                                    \
        __builtin_amdgcn_s_setprio(1);                                        \
        _Pragma("unroll")                                                     \
        for (int mf = 0; mf < 4; ++mf)                                        \
            _Pragma("unroll")                                                 \
            for (int nf = 0; nf < 4; ++nf)                                    \
                acc[mf][nf] = MF16(fa[mf], fb[nf], acc[mf][nf]);              \
        __builtin_amdgcn_s_setprio(0);                                        \
        asm volatile("s_waitcnt vmcnt(" VM ")" ::: "memory");                 \
        __builtin_amdgcn_s_barrier();                                         \
    }

    for (int tt = 0; tt < 12; tt += 3) {
        const int kk = (tt + 2) * 32;
        TB(0, 2, "4", true, kk)
        TB(1, 0, "4", true, kk + 32)
        TB(2, 1, "4", true, kk + 64)
    }
    TB(0, 2, "4", true, 14 * 32)
    TB(1, 0, "4", true, 15 * 32)
    TB(2, 0, "0", false, 0)
    TB(0, 0, "0", false, 0)
    #undef TB
    #undef STAGE
    #undef RD_A
    #undef RD_B

    #pragma unroll
    for (int nf = 0; nf < 4; ++nf) {
        const int col = n0 + wc * 64 + nf * 16 + l15;
        const float bv = boeff[col];
        #pragma unroll
        for (int mf = 0; mf < 4; ++mf) {
            const int row0 = m0 + wr * 64 + mf * 16 + l4 * 4;
            #pragma unroll
            for (int rr = 0; rr < 4; ++rr)
                out[(size_t)(row0 + rr) * 2048 + col] = acc[mf][nf][rr] + bv;
        }
    }
}

// ---------------- helpers for MFMA attention ----------------
__device__ __forceinline__ unsigned pkbf2(float a, float b)
{
    union { __bf16 h[2]; unsigned u; } x;
    x.h[0] = (__bf16)a; x.h[1] = (__bf16)b;
    return x.u;
}

#if __has_builtin(__builtin_amdgcn_permlane32_swap)
typedef unsigned int uint2v __attribute__((ext_vector_type(2)));
__device__ __forceinline__ void plswap(unsigned a, unsigned b, unsigned& w_lo, unsigned& w_hi, int)
{
    uint2v r = __builtin_amdgcn_permlane32_swap(a, b, false, false);
    w_lo = r[0]; w_hi = r[1];
}
#else
__device__ __forceinline__ void plswap(unsigned a, unsigned b, unsigned& w_lo, unsigned& w_hi, int hi)
{
    unsigned ax = (unsigned)__shfl_xor((int)a, 32);
    unsigned bx = (unsigned)__shfl_xor((int)b, 32);
    w_lo = hi ? bx : a;
    w_hi = hi ? b  : ax;
}
#endif

// ---------------- split-K causal flash attention + fused combine ----------------
// CHUNK = 256 keys; bh = blockIdx & 31 (XCD affinity). Fixed-m softmax.
// After storing partials, each wave increments cnt[bh*64+s] (device atomics);
// the LAST wave of a strip re-reads all partials (L2-hot) and writes normalized
// ao directly — attn_comb kernel eliminated. Deterministic: sums in index order.
__global__ __launch_bounds__(256)
void attn_part(const __bf16* __restrict__ qc, const __bf16* __restrict__ kc,
               const __bf16* __restrict__ vt,
               float* __restrict__ pl, __bf16* __restrict__ po,
               int* __restrict__ cnt, __bf16* __restrict__ ao)
{
    const int bh  = blockIdx.x & 31;
    const int t_  = blockIdx.x >> 5;                   // 0..71
    const int lin = t_ * 4 + (threadIdx.x >> 6);       // 0..287
    int g = (int)((sqrtf((float)lin + 1.0f) - 1.0f) * 0.5f);
    while (4 * (g + 1) * (g + 2) <= lin) ++g;
    while (4 * g * (g + 1) > lin) --g;
    const int rem = lin - 4 * g * (g + 1);
    const int sq  = rem / (g + 1);
    const int s   = 8 * g + sq;
    const int ci  = rem - sq * (g + 1);

    const int lane = threadIdx.x & 63;
    const int qcol = lane & 31;
    const int hi   = lane >> 5;

    const __bf16* qbase = qc + ((size_t)bh * LL + (size_t)s * 32) * 32;
    const __bf16* kbase = kc + (size_t)bh * LL * 32;
    const __bf16* vbase = vt + (size_t)bh * 32 * LL;

    const bf16x8 qf0 = *(const bf16x8*)(qbase + qcol * 32 + hi * 8);
    const bf16x8 qf1 = *(const bf16x8*)(qbase + qcol * 32 + 16 + hi * 8);

    const float M2 = 16.0f;            // fixed log2-domain max
    float lsum = 0.f;
    f32x16 O = {};

    const int t0 = ci * 8;
    const int t1 = min(s, t0 + 7);

    const __bf16* krow = kbase + (size_t)(t0 * 32 + qcol) * 32 + hi * 8;
    const __bf16* vrow = vbase + (size_t)qcol * LL + t0 * 32 + hi * 8;
    bf16x8 kc0 = *(const bf16x8*)(krow);
    bf16x8 kc1 = *(const bf16x8*)(krow + 16);
    bf16x8 vc0 = *(const bf16x8*)(vrow);
    bf16x8 vc1 = *(const bf16x8*)(vrow + 16);

    for (int t = t0; t <= t1; ++t) {
        const int tn = (t < t1) ? t + 1 : t;
        const __bf16* krn = kbase + (size_t)(tn * 32 + qcol) * 32 + hi * 8;
        const __bf16* vrn = vbase + (size_t)qcol * LL + tn * 32 + hi * 8;
        bf16x8 kn0 = *(const bf16x8*)(krn);
        bf16x8 kn1 = *(const bf16x8*)(krn + 16);
        bf16x8 vn0 = *(const bf16x8*)(vrn);
        bf16x8 vn1 = *(const bf16x8*)(vrn + 16);

        f32x16 S = {};
        S = __builtin_amdgcn_mfma_f32_32x32x16_bf16(kc0, qf0, S, 0, 0, 0);
        S = __builtin_amdgcn_mfma_f32_32x32x16_bf16(kc1, qf1, S, 0, 0, 0);

        if (t == s) {
            #pragma unroll
            for (int r = 0; r < 16; ++r) {
                const int kl = (r & 3) + 8 * (r >> 2) + 4 * hi;
                if (kl > qcol) S[r] = -1e30f;
            }
        }
        float p[16];
        #pragma unroll
        for (int r = 0; r < 16; ++r) { p[r] = exp2f(S[r] - M2); lsum += p[r]; }

        unsigned w[8];
        #pragma unroll
        for (int i = 0; i < 8; ++i) w[i] = pkbf2(p[2 * i], p[2 * i + 1]);
        union PF { unsigned u[4]; bf16x8 v; } pf1, pf2;
        plswap(w[0], w[2], pf1.u[0], pf1.u[2], hi);
        plswap(w[1], w[3], pf1.u[1], pf1.u[3], hi);
        plswap(w[4], w[6], pf2.u[0], pf2.u[2], hi);
        plswap(w[5], w[7], pf2.u[1], pf2.u[3], hi);

        O = __builtin_amdgcn_mfma_f32_32x32x16_bf16(vc0, pf1.v, O, 0, 0, 0);
        O = __builtin_amdgcn_mfma_f32_32x32x16_bf16(vc1, pf2.v, O, 0, 0, 0);

        kc0 = kn0; kc1 = kn1; vc0 = vn0; vc1 = vn1;
    }

    const float L = lsum + __shfl_xor(lsum, 32);
    const size_t gq = (size_t)bh * LL + (size_t)s * 32 + qcol;
    const size_t slot = gq * 8 + ci;
    if (hi == 0) pl[slot] = L;
    __bf16* pp = po + slot * 32;
    #pragma unroll
    for (int g4 = 0; g4 < 4; ++g4) {
        bf16x4 pk = { (__bf16)O[g4 * 4 + 0], (__bf16)O[g4 * 4 + 1],
                      (__bf16)O[g4 * 4 + 2], (__bf16)O[g4 * 4 + 3] };
        *(bf16x4*)(pp + g4 * 8 + 4 * hi) = pk;
    }

    // ---- completion counting + fused combine (last wave of the strip) ----
    const int nch = (s >> 3) + 1;
    __threadfence();                                   // publish po/pl (release)
    int old = 0;
    if (lane == 0) old = atomicAdd(&cnt[bh * 64 + s], 1);
    old = __builtin_amdgcn_readfirstlane(old);
    if (old == nch - 1) {
        __threadfence();                               // acquire: see all partials
        const int q = lane & 31;
        const size_t gq2 = (size_t)bh * LL + (size_t)s * 32 + q;
        float Lt = 0.f;
        float ov[16] = {};
        for (int c = 0; c < nch; ++c) {
            Lt += pl[gq2 * 8 + c];
            const __bf16* p2 = po + (gq2 * 8 + c) * 32 + hi * 16;
            bf16x8 v0 = *(const bf16x8*)(p2);
            bf16x8 v1 = *(const bf16x8*)(p2 + 8);
            #pragma unroll
            for (int jj = 0; jj < 8; ++jj) {
                ov[jj]     += (float)v0[jj];
                ov[8 + jj] += (float)v1[jj];
            }
        }
        const float inv = 1.f / Lt;
        __bf16* aor = ao + gq2 * 32 + hi * 16;
        #pragma unroll
        for (int d8 = 0; d8 < 2; ++d8) {
            bf16x8 vv;
            #pragma unroll
            for (int jj = 0; jj < 8; ++jj) vv[jj] = (__bf16)(ov[d8 * 8 + jj] * inv);
            *(bf16x8*)(aor + d8 * 8) = vv;
        }
    }
}

extern "C" void kernel_launch(void* const* d_in, const int* in_sizes, int n_in,
                              void* d_out, int out_size, void* d_ws, size_t ws_size,
                              hipStream_t stream)
{
    const float* x   = (const float*)d_in[0];
    const float* fc  = (const float*)d_in[1];
    const float* Wq  = (const float*)d_in[2];
    const float* bq  = (const float*)d_in[3];
    const float* Wk  = (const float*)d_in[4];
    const float* bk  = (const float*)d_in[5];
    const float* Wv  = (const float*)d_in[6];
    const float* bv  = (const float*)d_in[7];
    const float* Wqc = (const float*)d_in[8];
    const float* bqc = (const float*)d_in[9];
    const float* Wkc = (const float*)d_in[10];
    const float* bkc = (const float*)d_in[11];
    const float* Wvc = (const float*)d_in[12];
    const float* bvc = (const float*)d_in[13];
    const float* Wd  = (const float*)d_in[14];
    const float* bd  = (const float*)d_in[15];
    const float* Wo  = (const float*)d_in[16];
    const float* bo  = (const float*)d_in[17];
    float* out = (float*)d_out;

    const size_t MB = 1048576;
    char* w = (char*)d_ws;
    __bf16* xb    = (__bf16*)(w);             // 16 MiB, dead after gemm_qkv
    __bf16* Wqb   = (__bf16*)(w + 16 * MB);   // 8 MiB
    __bf16* Wkb   = (__bf16*)(w + 24 * MB);   // 8 MiB
    __bf16* Wveff = (__bf16*)(w + 32 * MB);   // 2 MiB
    __bf16* qcbf  = (__bf16*)(w + 66 * MB);   // 4 MiB
    __bf16* kcbf  = (__bf16*)(w + 70 * MB);   // 4 MiB
    __bf16* vtbf  = (__bf16*)(w + 74 * MB);   // 4 MiB
    __bf16* aobf  = (__bf16*)(w + 78 * MB);   // 4 MiB
    __bf16* Wqcb  = (__bf16*)(w + 82 * MB);   // 8 KiB
    __bf16* Wkcb  = (__bf16*)(w + 82 * MB + 8192);
    __bf16* Woeff = (__bf16*)(w + 83 * MB);   // 2 MiB
    float*  boeff = (float*)(w + 85 * MB);    // 8 KiB
    float*  bveff = (float*)(w + 85 * MB + 8192);

    // attention partials alias [0, 34 MiB) (dead by attention):
    __bf16* po  = (__bf16*)d_ws;                    // 32 MiB
    float*  pl  = (float*)(w + 32 * MB);            // 2 MiB
    int*    cnt = (int*)(w + 35 * MB);              // 8 KiB (35-66 MiB hole is unused)

    if (ws_size < (size_t)90 * MB) return;

    setup_all<<<17481, 256, 0, stream>>>(x, Wq, Wk, Wqc, Wkc, Wv, Wvc, bv, bvc,
                                         Wo, Wd, bd, bo,
                                         xb, Wqb, Wkb, Wqcb, Wkcb,
                                         Wveff, bveff, Woeff, boeff, cnt);

    gemm_qkv<<<576, 256, 0, stream>>>(xb, Wqb, Wkb, Wveff, bq, bk, bveff,
                                      Wqcb, Wkcb, bqc, bkc, fc, qcbf, kcbf, vtbf);

    attn_part<<<2304, 256, 0, stream>>>(qcbf, kcbf, vtbf, pl, po, cnt, aobf);

    gemm_ao<<<512, 256, 0, stream>>>(aobf, Woeff, boeff, out);
}

// Round 23
// 215.402 us; speedup vs baseline: 2.8689x; 2.8689x over previous
//
#include <hip/hip_runtime.h>

typedef __attribute__((ext_vector_type(8))) __bf16 bf16x8;
typedef __attribute__((ext_vector_type(4))) __bf16 bf16x4;
typedef __attribute__((ext_vector_type(4))) float f32x4;
typedef __attribute__((ext_vector_type(16))) float f32x16;

#define LL 2048
#define DD 2048
#define HH 16
#define HDIM 128

// ---------------- merged setup: conversions + effective-weight builders --------
__global__ __launch_bounds__(256)
void setup_all(const float* __restrict__ x, const float* __restrict__ Wq,
               const float* __restrict__ Wk, const float* __restrict__ Wqc,
               const float* __restrict__ Wkc,
               const float* __restrict__ Wv, const float* __restrict__ Wvc,
               const float* __restrict__ bv, const float* __restrict__ bvc,
               const float* __restrict__ Wo, const float* __restrict__ Wd,
               const float* __restrict__ bd, const float* __restrict__ bo,
               __bf16* __restrict__ xb, __bf16* __restrict__ Wqb, __bf16* __restrict__ Wkb,
               __bf16* __restrict__ Wqcb, __bf16* __restrict__ Wkcb,
               __bf16* __restrict__ Wveff, float* __restrict__ bveff,
               __bf16* __restrict__ Woeff, float* __restrict__ boeff)
{
    __shared__ float sm[128 * 32];
    const int tid = threadIdx.x;
    const int bid = blockIdx.x;

    if (bid < 16392) {                                    // fp32 -> bf16 conversions
        size_t i = (size_t)bid * 256 + tid;
        const float* s; __bf16* d; size_t off;
        if (i < 2097152)      { s = x;   d = xb;   off = i; }
        else if (i < 3145728) { s = Wq;  d = Wqb;  off = i - 2097152; }
        else if (i < 4194304) { s = Wk;  d = Wkb;  off = i - 3145728; }
        else if (i < 4195328) { s = Wqc; d = Wqcb; off = i - 4194304; }
        else                  { s = Wkc; d = Wkcb; off = i - 4195328; }
        float4 v = *(const float4*)(s + off * 4);
        bf16x4 o = { (__bf16)v.x, (__bf16)v.y, (__bf16)v.z, (__bf16)v.w };
        *(bf16x4*)(d + off * 4) = o;
        return;
    }
    int idx = bid - 16392;
    if (idx < 512) {                                      // Wv_eff
        float (*WvcT)[32] = (float(*)[32])sm;             // [j][o]
        const int h = idx >> 5, dc = idx & 31;
        for (int i = tid; i < 4096; i += 256) WvcT[i & 127][i >> 7] = Wvc[i];
        __syncthreads();
        const int d  = dc * 64 + (tid & 63);
        const int o0 = (tid >> 6) * 8;
        float acc[8] = {};
        for (int jj = 0; jj < 128; ++jj) {
            const float w = Wv[(size_t)(h * 128 + jj) * 2048 + d];
            #pragma unroll
            for (int o = 0; o < 8; ++o) acc[o] += WvcT[jj][o0 + o] * w;
        }
        #pragma unroll
        for (int o = 0; o < 8; ++o)
            Wveff[(size_t)(h * 32 + o0 + o) * 2048 + d] = (__bf16)acc[o];
        if (dc == 0 && tid < 32) {
            float s = bvc[tid];
            for (int jj = 0; jj < 128; ++jj) s += WvcT[jj][tid] * bv[h * 128 + jj];
            bveff[h * 32 + tid] = s;
        }
        return;
    }
    idx -= 512;
    if (idx < 512) {                                      // Wo_eff
        float (*WdL)[32] = (float(*)[32])sm;              // [u][o]
        const int dc = idx & 31, h = idx >> 5;
        for (int i = tid; i < 4096; i += 256) WdL[i >> 5][i & 31] = Wd[i];
        __syncthreads();
        const int dout = dc * 64 + (tid & 63);
        const int o0   = (tid >> 6) * 8;
        float acc[8] = {};
        const float* wrow = Wo + (size_t)dout * 2048 + h * 128;
        for (int u = 0; u < 128; ++u) {
            const float w = wrow[u];
            #pragma unroll
            for (int o = 0; o < 8; ++o) acc[o] += WdL[u][o0 + o] * w;
        }
        #pragma unroll
        for (int o = 0; o < 8; ++o)
            Woeff[(size_t)dout * 512 + h * 32 + o0 + o] = (__bf16)acc[o];
        return;
    }
    idx -= 512;                                           // bo_eff
    float* bdL = sm;
    if (tid < 128) bdL[tid] = bd[tid];
    __syncthreads();
    const int d  = idx * 32 + (tid >> 3);
    const int s0 = (tid & 7) * 64;
    float s = 0.f;
    const float* wrow = Wo + (size_t)d * 2048 + s0 * 4;
    for (int c4 = 0; c4 < 64; ++c4) {
        float4 wv = *(const float4*)(wrow + c4 * 4);
        const int cb = ((s0 + c4) * 4) & 127;
        s += wv.x * bdL[cb] + wv.y * bdL[cb + 1] + wv.z * bdL[cb + 2] + wv.w * bdL[cb + 3];
    }
    #pragma unroll
    for (int off = 4; off; off >>= 1) s += __shfl_down(s, off, 8);
    if ((tid & 7) == 0) boeff[d] = bo[d] + s;
}

// ---------------- global -> LDS async 16B ----------------
typedef unsigned int u32;
typedef const __attribute__((address_space(1))) u32* gp_t;
typedef __attribute__((address_space(3))) u32* lp_t;
__device__ __forceinline__ void gload16(const __bf16* g, __bf16* l)
{
    __builtin_amdgcn_global_load_lds((gp_t)(const void*)g, (lp_t)(void*)l, 16, 0, 0);
}

#define MF16(a, b, c) __builtin_amdgcn_mfma_f32_16x16x32_bf16(a, b, c, 0, 0, 0)

// ====== 128x256-tile fused QKV GEMM + in-epilogue RoPE+latproj (q,k) ============
__global__ __launch_bounds__(256, 2)
void gemm_qkv(const __bf16* __restrict__ A,
              const __bf16* __restrict__ Wq, const __bf16* __restrict__ Wk,
              const __bf16* __restrict__ Wveff,
              const float* __restrict__ bq, const float* __restrict__ bk,
              const float* __restrict__ bveff,
              const __bf16* __restrict__ Wqcb, const __bf16* __restrict__ Wkcb,
              const float* __restrict__ bqc, const float* __restrict__ bkc,
              const float* __restrict__ fc,
              __bf16* __restrict__ qc, __bf16* __restrict__ kc, __bf16* __restrict__ vt)
{
    __shared__ __bf16 lds[3][12288];    // per buf: A[128][32] @0, B[256][32] @4096

    const int bid = blockIdx.x;                 // 576
    const int xcd = bid & 7;
    const int j   = bid >> 3;                   // 0..71
    const int bx  = j >> 2;                     // 0..17
    const int byl = j & 3;
    const int by  = xcd * 4 + byl;              // 0..31
    const int m0  = by * 128;
    const int which = (bx >= 16) ? 2 : (bx >> 3);
    const int n0  = (which == 2) ? (bx - 16) * 256 : (bx & 7) * 256;
    const __bf16* W = which == 0 ? Wq : which == 1 ? Wk : Wveff;

    const int tid  = threadIdx.x;
    const int wid  = tid >> 6;
    const int lane = tid & 63;
    const int wr   = wid >> 1;
    const int wc   = wid & 1;
    const int l15  = lane & 15;
    const int l4   = lane >> 4;
    const int swz  = (l4 ^ (l15 & 3) ^ ((l15 >> 2) & 3)) * 8;

    const int srl  = lane >> 2;
    const int scol = ((lane & 3) ^ (srl & 3) ^ ((srl >> 2) & 3)) * 8;
    const __bf16* gA0 = A + (size_t)(m0 + wid * 32 + srl) * 2048 + scol;
    const __bf16* gB0 = W + (size_t)(n0 + wid * 64 + srl) * 2048 + scol;

    #define STAGE(bb, kk)                                                \
    {   __bf16* dA = &lds[bb][wid * 1024];                               \
        __bf16* dB = &lds[bb][4096 + wid * 2048];                        \
        gload16(gA0 + (kk), dA);                                         \
        gload16(gA0 + (size_t)16 * 2048 + (kk), dA + 512);               \
        gload16(gB0 + (kk), dB);                                         \
        gload16(gB0 + (size_t)16 * 2048 + (kk), dB + 512);               \
        gload16(gB0 + (size_t)32 * 2048 + (kk), dB + 1024);              \
        gload16(gB0 + (size_t)48 * 2048 + (kk), dB + 1536);              \
    }
    #define RD_A(bb, mf) (*(const bf16x8*)&lds[bb][(wr * 64 + (mf) * 16 + l15) * 32 + swz])
    #define RD_B(bb, nf) (*(const bf16x8*)&lds[bb][4096 + (wc * 128 + (nf) * 16 + l15) * 32 + swz])

    f32x4 acc[4][8] = {};

    STAGE(0, 0) STAGE(1, 32)
    asm volatile("s_waitcnt vmcnt(6)" ::: "memory");
    __builtin_amdgcn_s_barrier();

    #define TB(RB, SB, VM, DOST, kk)                                          \
    {                                                                         \
        bf16x8 fa[4], fb[8];                                                  \
        fa[0] = RD_A(RB, 0); fa[1] = RD_A(RB, 1);                             \
        fa[2] = RD_A(RB, 2); fa[3] = RD_A(RB, 3);                             \
        fb[0] = RD_B(RB, 0); fb[1] = RD_B(RB, 1);                             \
        fb[2] = RD_B(RB, 2); fb[3] = RD_B(RB, 3);                             \
        fb[4] = RD_B(RB, 4); fb[5] = RD_B(RB, 5);                             \
        fb[6] = RD_B(RB, 6); fb[7] = RD_B(RB, 7);                             \
        if (DOST) STAGE(SB, kk)                                               \
        asm volatile("s_waitcnt lgkmcnt(0)" ::: "memory");                    \
        __builtin_amdgcn_sched_barrier(0);                                    \
        __builtin_amdgcn_s_setprio(1);                                        \
        _Pragma("unroll")                                                     \
        for (int mf = 0; mf < 4; ++mf)                                        \
            _Pragma("unroll")                                                 \
            for (int nf = 0; nf < 8; ++nf)                                    \
                acc[mf][nf] = MF16(fa[mf], fb[nf], acc[mf][nf]);              \
        __builtin_amdgcn_s_setprio(0);                                        \
        asm volatile("s_waitcnt vmcnt(" VM ")" ::: "memory");                 \
        __builtin_amdgcn_s_barrier();                                         \
    }

    for (int tt = 0; tt < 60; tt += 3) {
        const int kk = (tt + 2) * 32;
        TB(0, 2, "6", true, kk)
        TB(1, 0, "6", true, kk + 32)
        TB(2, 1, "6", true, kk + 64)
    }
    TB(0, 2, "6", true, 62 * 32)
    TB(1, 0, "6", true, 63 * 32)
    TB(2, 0, "0", false, 0)
    TB(0, 0, "0", false, 0)
    #undef TB
    #undef STAGE
    #undef RD_A
    #undef RD_B

    if (which < 2) {
        __bf16* qt = &lds[0][0];                // [128][136]
        const float* bb_ = which ? bk : bq;
        const __bf16* Wb = which ? Wkcb : Wqcb;
        const float*  bs = which ? bkc : bqc;
        const int o   = lane & 31;
        const int hi  = lane >> 5;
        const int b   = m0 >> 11;
        const int l0b = m0 & 2047;
        const int lrow = wid * 32 + o;
        const int l    = l0b + lrow;
        const float* fcr = fc + (size_t)l * 128;
        const float QSCALE = 0.17677669529663689f * 1.44269504088896340f;
        __bf16* outp = which ? kc : qc;

        bf16x8 wf[8];
        #pragma unroll
        for (int ks = 0; ks < 8; ++ks)
            wf[ks] = *(const bf16x8*)(Wb + o * 128 + ks * 16 + hi * 8);

        #pragma unroll
        for (int half = 0; half < 2; ++half) {
            if (wc == half) {
                #pragma unroll
                for (int nf = 0; nf < 8; ++nf) {
                    const int col = nf * 16 + l15;
                    const float bv = bb_[n0 + half * 128 + col];
                    #pragma unroll
                    for (int mf = 0; mf < 4; ++mf) {
                        const int row0 = wr * 64 + mf * 16 + l4 * 4;
                        #pragma unroll
                        for (int rr = 0; rr < 4; ++rr)
                            qt[(row0 + rr) * 136 + col] = (__bf16)(acc[mf][nf][rr] + bv);
                    }
                }
            }
            __syncthreads();

            const int h = (n0 >> 7) + half;
            f32x16 C = {};
            #pragma unroll
            for (int ks = 0; ks < 8; ++ks) {
                bf16x8 af = *(const bf16x8*)&qt[lrow * 136 + ks * 16 + hi * 8];
                const float4 cA = *(const float4*)(fcr + (ks * 8 + hi * 4) * 2);
                const float4 cB = *(const float4*)(fcr + (ks * 8 + hi * 4) * 2 + 4);
                float a, b_;
                a = (float)af[0]; b_ = (float)af[1];
                af[0] = (__bf16)(a * cA.x - b_ * cA.y); af[1] = (__bf16)(a * cA.y + b_ * cA.x);
                a = (float)af[2]; b_ = (float)af[3];
                af[2] = (__bf16)(a * cA.z - b_ * cA.w); af[3] = (__bf16)(a * cA.w + b_ * cA.z);
                a = (float)af[4]; b_ = (float)af[5];
                af[4] = (__bf16)(a * cB.x - b_ * cB.y); af[5] = (__bf16)(a * cB.y + b_ * cB.x);
                a = (float)af[6]; b_ = (float)af[7];
                af[6] = (__bf16)(a * cB.z - b_ * cB.w); af[7] = (__bf16)(a * cB.w + b_ * cB.z);
                C = __builtin_amdgcn_mfma_f32_32x32x16_bf16(af, wf[ks], C, 0, 0, 0);
            }

            const float bias = bs[o];
            const size_t g0row = (size_t)(b * 16 + h) * 2048 + l0b + wid * 32;
            #pragma unroll
            for (int r = 0; r < 16; ++r) {
                const int ro = (r & 3) + 8 * (r >> 2) + 4 * hi;
                float v = C[r] + bias;
                if (which == 0) v *= QSCALE;
                outp[(g0row + ro) * 32 + o] = (__bf16)v;
            }
            __syncthreads();
        }
    } else {
        #pragma unroll
        for (int nf = 0; nf < 8; ++nf) {
            const int ncol = n0 + wc * 128 + nf * 16 + l15;
            const float bv = bveff[ncol];
            const int hh = ncol >> 5, oo = ncol & 31;
            #pragma unroll
            for (int mf = 0; mf < 4; ++mf) {
                const int row0 = m0 + wr * 64 + mf * 16 + l4 * 4;
                const int b = row0 >> 11, l0 = row0 & 2047;
                bf16x4 pk = { (__bf16)(acc[mf][nf][0] + bv), (__bf16)(acc[mf][nf][1] + bv),
                              (__bf16)(acc[mf][nf][2] + bv), (__bf16)(acc[mf][nf][3] + bv) };
                *(bf16x4*)(vt + ((size_t)((b * 16 + hh) * 32 + oo)) * 2048 + l0) = pk;
            }
        }
    }
}

// Final GEMM with counted-vmcnt depth-2 pipeline: out = ao@Woeff^T + bo_eff.
// 512 blocks; by = xcd*4 + (jj&3) -> per-XCD A-slice 512 KB L2-resident.
__global__ __launch_bounds__(256, 3)
void gemm_ao(const __bf16* __restrict__ ao, const __bf16* __restrict__ Woeff,
             const float* __restrict__ boeff, float* __restrict__ out)
{
    __shared__ __bf16 lds[3][2][4096];          // [buf][A|B][128 rows x 32 cols]
    const int bid = blockIdx.x;                 // 512
    const int xcd = bid & 7;
    const int jj  = bid >> 3;                   // 0..63
    const int by  = xcd * 4 + (jj & 3);         // 0..31
    const int bx  = jj >> 2;                    // 0..15
    const int m0  = by * 128;
    const int n0  = bx * 128;

    const int tid  = threadIdx.x;
    const int wid  = tid >> 6;
    const int lane = tid & 63;
    const int wr   = wid >> 1;
    const int wc   = wid & 1;
    const int l15  = lane & 15;
    const int l4   = lane >> 4;
    const int swz  = (l4 ^ (l15 & 3) ^ ((l15 >> 2) & 3)) * 8;

    const int srl  = lane >> 2;
    const int scol = ((lane & 3) ^ (srl & 3) ^ ((srl >> 2) & 3)) * 8;
    const int r0   = m0 + wid * 32 + srl;
    const int b0   = r0 >> 11, li0 = r0 & 2047;
    const __bf16* gA0 = ao + ((size_t)(b0 << 4) * 2048 + li0) * 32 + scol;
    const __bf16* gA1 = ao + ((size_t)(b0 << 4) * 2048 + li0 + 16) * 32 + scol;
    const __bf16* gB0 = Woeff + (size_t)(n0 + wid * 32 + srl) * 512 + scol;

    #define STAGE(bb, kk)                                                     \
    {   __bf16* dA = &lds[bb][0][wid * 1024];                                 \
        __bf16* dB = &lds[bb][1][wid * 1024];                                 \
        const size_t ka = (size_t)((kk) >> 5) * 65536;                        \
        gload16(gA0 + ka, dA);                                                \
        gload16(gA1 + ka, dA + 512);                                          \
        gload16(gB0 + (kk), dB);                                              \
        gload16(gB0 + (size_t)16 * 512 + (kk), dB + 512);                     \
    }
    #define RD_A(bb, mf) (*(const bf16x8*)&lds[bb][0][(wr * 64 + (mf) * 16 + l15) * 32 + swz])
    #define RD_B(bb, nf) (*(const bf16x8*)&lds[bb][1][(wc * 64 + (nf) * 16 + l15) * 32 + swz])

    f32x4 acc[4][4] = {};

    STAGE(0, 0) STAGE(1, 32)
    asm volatile("s_waitcnt vmcnt(4)" ::: "memory");
    __builtin_amdgcn_s_barrier();

    #define TB(RB, SB, VM, DOST, kk)                                          \
    {                                                                         \
        bf16x8 fa[4], fb[4];                                                  \
        fa[0] = RD_A(RB, 0); fa[1] = RD_A(RB, 1);                             \
        fa[2] = RD_A(RB, 2); fa[3] = RD_A(RB, 3);                             \
        fb[0] = RD_B(RB, 0); fb[1] = RD_B(RB, 1);                             \
        fb[2] = RD_B(RB, 2); fb[3] = RD_B(RB, 3);                             \
        if (DOST) STAGE(SB, kk)                                               \
        asm volatile("s_waitcnt lgkmcnt(0)" ::: "memory");                    \
        __builtin_amdgcn_sched_barrier(0);                                    \
        __builtin_amdgcn_s_setprio(1);                                        \
        _Pragma("unroll")                                                     \
        for (int mf = 0; mf < 4; ++mf)                                        \
            _Pragma("unroll")                                                 \
            for (int nf = 0; nf < 4; ++nf)                                    \
                acc[mf][nf] = MF16(fa[mf], fb[nf], acc[mf][nf]);              \
        __builtin_amdgcn_s_setprio(0);                                        \
        asm volatile("s_waitcnt vmcnt(" VM ")" ::: "memory");                 \
        __builtin_amdgcn_s_barrier();                                         \
    }

    for (int tt = 0; tt < 12; tt += 3) {
        const int kk = (tt + 2) * 32;
        TB(0, 2, "4", true, kk)
        TB(1, 0, "4", true, kk + 32)
        TB(2, 1, "4", true, kk + 64)
    }
    TB(0, 2, "4", true, 14 * 32)
    TB(1, 0, "4", true, 15 * 32)
    TB(2, 0, "0", false, 0)
    TB(0, 0, "0", false, 0)
    #undef TB
    #undef STAGE
    #undef RD_A
    #undef RD_B

    #pragma unroll
    for (int nf = 0; nf < 4; ++nf) {
        const int col = n0 + wc * 64 + nf * 16 + l15;
        const float bv = boeff[col];
        #pragma unroll
        for (int mf = 0; mf < 4; ++mf) {
            const int row0 = m0 + wr * 64 + mf * 16 + l4 * 4;
            #pragma unroll
            for (int rr = 0; rr < 4; ++rr)
                out[(size_t)(row0 + rr) * 2048 + col] = acc[mf][nf][rr] + bv;
        }
    }
}

// ---------------- helpers for MFMA attention ----------------
__device__ __forceinline__ unsigned pkbf2(float a, float b)
{
    union { __bf16 h[2]; unsigned u; } x;
    x.h[0] = (__bf16)a; x.h[1] = (__bf16)b;
    return x.u;
}

#if __has_builtin(__builtin_amdgcn_permlane32_swap)
typedef unsigned int uint2v __attribute__((ext_vector_type(2)));
__device__ __forceinline__ void plswap(unsigned a, unsigned b, unsigned& w_lo, unsigned& w_hi, int)
{
    uint2v r = __builtin_amdgcn_permlane32_swap(a, b, false, false);
    w_lo = r[0]; w_hi = r[1];
}
#else
__device__ __forceinline__ void plswap(unsigned a, unsigned b, unsigned& w_lo, unsigned& w_hi, int hi)
{
    unsigned ax = (unsigned)__shfl_xor((int)a, 32);
    unsigned bx = (unsigned)__shfl_xor((int)b, 32);
    w_lo = hi ? bx : a;
    w_hi = hi ? b  : ax;
}
#endif

// ---------------- split-K causal flash attention via MFMA ----------------
// CHUNK = 256 keys; 2304 blocks = 72 t x 32 bh with bh = blockIdx & 31:
// all 4 waves of a block share bh, and blockIdx%8 == bh%8 -> per-XCD working
// set = 4 bh x (qc+kc+vt = 384 KB) = 1.5 MB, L2-resident.
__global__ __launch_bounds__(256)
void attn_part(const __bf16* __restrict__ qc, const __bf16* __restrict__ kc,
               const __bf16* __restrict__ vt,
               float* __restrict__ pl, __bf16* __restrict__ po)
{
    const int bh  = blockIdx.x & 31;
    const int t_  = blockIdx.x >> 5;                   // 0..71
    const int lin = t_ * 4 + (threadIdx.x >> 6);       // 0..287
    int g = (int)((sqrtf((float)lin + 1.0f) - 1.0f) * 0.5f);
    while (4 * (g + 1) * (g + 2) <= lin) ++g;
    while (4 * g * (g + 1) > lin) --g;
    const int rem = lin - 4 * g * (g + 1);
    const int sq  = rem / (g + 1);
    const int s   = 8 * g + sq;
    const int ci  = rem - sq * (g + 1);

    const int lane = threadIdx.x & 63;
    const int qcol = lane & 31;
    const int hi   = lane >> 5;

    const __bf16* qbase = qc + ((size_t)bh * LL + (size_t)s * 32) * 32;
    const __bf16* kbase = kc + (size_t)bh * LL * 32;
    const __bf16* vbase = vt + (size_t)bh * 32 * LL;

    const bf16x8 qf0 = *(const bf16x8*)(qbase + qcol * 32 + hi * 8);
    const bf16x8 qf1 = *(const bf16x8*)(qbase + qcol * 32 + 16 + hi * 8);

    const float M2 = 16.0f;            // fixed log2-domain max
    float lsum = 0.f;
    f32x16 O = {};

    const int t0 = ci * 8;
    const int t1 = min(s, t0 + 7);

    const __bf16* krow = kbase + (size_t)(t0 * 32 + qcol) * 32 + hi * 8;
    const __bf16* vrow = vbase + (size_t)qcol * LL + t0 * 32 + hi * 8;
    bf16x8 kc0 = *(const bf16x8*)(krow);
    bf16x8 kc1 = *(const bf16x8*)(krow + 16);
    bf16x8 vc0 = *(const bf16x8*)(vrow);
    bf16x8 vc1 = *(const bf16x8*)(vrow + 16);

    for (int t = t0; t <= t1; ++t) {
        const int tn = (t < t1) ? t + 1 : t;
        const __bf16* krn = kbase + (size_t)(tn * 32 + qcol) * 32 + hi * 8;
        const __bf16* vrn = vbase + (size_t)qcol * LL + tn * 32 + hi * 8;
        bf16x8 kn0 = *(const bf16x8*)(krn);
        bf16x8 kn1 = *(const bf16x8*)(krn + 16);
        bf16x8 vn0 = *(const bf16x8*)(vrn);
        bf16x8 vn1 = *(const bf16x8*)(vrn + 16);

        f32x16 S = {};
        S = __builtin_amdgcn_mfma_f32_32x32x16_bf16(kc0, qf0, S, 0, 0, 0);
        S = __builtin_amdgcn_mfma_f32_32x32x16_bf16(kc1, qf1, S, 0, 0, 0);

        if (t == s) {
            #pragma unroll
            for (int r = 0; r < 16; ++r) {
                const int kl = (r & 3) + 8 * (r >> 2) + 4 * hi;
                if (kl > qcol) S[r] = -1e30f;
            }
        }
        float p[16];
        #pragma unroll
        for (int r = 0; r < 16; ++r) { p[r] = exp2f(S[r] - M2); lsum += p[r]; }

        unsigned w[8];
        #pragma unroll
        for (int i = 0; i < 8; ++i) w[i] = pkbf2(p[2 * i], p[2 * i + 1]);
        union PF { unsigned u[4]; bf16x8 v; } pf1, pf2;
        plswap(w[0], w[2], pf1.u[0], pf1.u[2], hi);
        plswap(w[1], w[3], pf1.u[1], pf1.u[3], hi);
        plswap(w[4], w[6], pf2.u[0], pf2.u[2], hi);
        plswap(w[5], w[7], pf2.u[1], pf2.u[3], hi);

        O = __builtin_amdgcn_mfma_f32_32x32x16_bf16(vc0, pf1.v, O, 0, 0, 0);
        O = __builtin_amdgcn_mfma_f32_32x32x16_bf16(vc1, pf2.v, O, 0, 0, 0);

        kc0 = kn0; kc1 = kn1; vc0 = vn0; vc1 = vn1;
    }

    const float L = lsum + __shfl_xor(lsum, 32);
    const size_t gq = (size_t)bh * LL + (size_t)s * 32 + qcol;
    const size_t slot = gq * 8 + ci;
    if (hi == 0) pl[slot] = L;
    __bf16* pp = po + slot * 32;
    #pragma unroll
    for (int g4 = 0; g4 < 4; ++g4) {
        bf16x4 pk = { (__bf16)O[g4 * 4 + 0], (__bf16)O[g4 * 4 + 1],
                      (__bf16)O[g4 * 4 + 2], (__bf16)O[g4 * 4 + 3] };
        *(bf16x4*)(pp + g4 * 8 + 4 * hi) = pk;
    }
}

// ---------------- attention combine (plain sum, bf16 partials) -> bf16 ao ------
__global__ __launch_bounds__(256)
void attn_comb(const float* __restrict__ pl, const __bf16* __restrict__ po,
               __bf16* __restrict__ ao)
{
    const int g = blockIdx.x * 256 + threadIdx.x;   // 0..65535
    const int i = g & (LL - 1);
    const int nch = (i >> 8) + 1;                   // chunks of 256 keys
    float L = 0.f;
    float o[32] = {};
    for (int c = 0; c < nch; ++c) {
        L += pl[(size_t)g * 8 + c];
        const __bf16* pp = po + ((size_t)g * 8 + c) * 32;
        #pragma unroll
        for (int d8 = 0; d8 < 4; ++d8) {
            bf16x8 v = *(const bf16x8*)(pp + d8 * 8);
            #pragma unroll
            for (int jj = 0; jj < 8; ++jj) o[d8 * 8 + jj] += (float)v[jj];
        }
    }
    const float inv = 1.f / L;
    #pragma unroll
    for (int d8 = 0; d8 < 4; ++d8) {
        bf16x8 v;
        #pragma unroll
        for (int jj = 0; jj < 8; ++jj) v[jj] = (__bf16)(o[d8 * 8 + jj] * inv);
        *(bf16x8*)(ao + (size_t)g * 32 + d8 * 8) = v;
    }
}

extern "C" void kernel_launch(void* const* d_in, const int* in_sizes, int n_in,
                              void* d_out, int out_size, void* d_ws, size_t ws_size,
                              hipStream_t stream)
{
    const float* x   = (const float*)d_in[0];
    const float* fc  = (const float*)d_in[1];
    const float* Wq  = (const float*)d_in[2];
    const float* bq  = (const float*)d_in[3];
    const float* Wk  = (const float*)d_in[4];
    const float* bk  = (const float*)d_in[5];
    const float* Wv  = (const float*)d_in[6];
    const float* bv  = (const float*)d_in[7];
    const float* Wqc = (const float*)d_in[8];
    const float* bqc = (const float*)d_in[9];
    const float* Wkc = (const float*)d_in[10];
    const float* bkc = (const float*)d_in[11];
    const float* Wvc = (const float*)d_in[12];
    const float* bvc = (const float*)d_in[13];
    const float* Wd  = (const float*)d_in[14];
    const float* bd  = (const float*)d_in[15];
    const float* Wo  = (const float*)d_in[16];
    const float* bo  = (const float*)d_in[17];
    float* out = (float*)d_out;

    const size_t MB = 1048576;
    char* w = (char*)d_ws;
    __bf16* xb    = (__bf16*)(w);             // 16 MiB, dead after gemm_qkv
    __bf16* Wqb   = (__bf16*)(w + 16 * MB);   // 8 MiB
    __bf16* Wkb   = (__bf16*)(w + 24 * MB);   // 8 MiB
    __bf16* Wveff = (__bf16*)(w + 32 * MB);   // 2 MiB
    __bf16* qcbf  = (__bf16*)(w + 66 * MB);   // 4 MiB
    __bf16* kcbf  = (__bf16*)(w + 70 * MB);   // 4 MiB
    __bf16* vtbf  = (__bf16*)(w + 74 * MB);   // 4 MiB
    __bf16* aobf  = (__bf16*)(w + 78 * MB);   // 4 MiB
    __bf16* Wqcb  = (__bf16*)(w + 82 * MB);   // 8 KiB
    __bf16* Wkcb  = (__bf16*)(w + 82 * MB + 8192);
    __bf16* Woeff = (__bf16*)(w + 83 * MB);   // 2 MiB
    float*  boeff = (float*)(w + 85 * MB);    // 8 KiB
    float*  bveff = (float*)(w + 85 * MB + 8192);

    // attention partials alias [0, 34 MiB) (dead by attention):
    __bf16* po = (__bf16*)d_ws;                     // 32 MiB
    float*  pl = (float*)(w + 32 * MB);             // 2 MiB

    if (ws_size < (size_t)90 * MB) return;

    setup_all<<<17480, 256, 0, stream>>>(x, Wq, Wk, Wqc, Wkc, Wv, Wvc, bv, bvc,
                                         Wo, Wd, bd, bo,
                                         xb, Wqb, Wkb, Wqcb, Wkcb,
                                         Wveff, bveff, Woeff, boeff);

    gemm_qkv<<<576, 256, 0, stream>>>(xb, Wqb, Wkb, Wveff, bq, bk, bveff,
                                      Wqcb, Wkcb, bqc, bkc, fc, qcbf, kcbf, vtbf);

    attn_part<<<2304, 256, 0, stream>>>(qcbf, kcbf, vtbf, pl, po);
    attn_comb<<<256, 256, 0, stream>>>(pl, po, aobf);

    gemm_ao<<<512, 256, 0, stream>>>(aobf, Woeff, boeff, out);
}